// Round 6
// baseline (350.617 us; speedup 1.0000x reference)
//
#include <hip/hip_runtime.h>

// Problem constants
#define QDIM   45184      // 64*64*9 + 64 + 2*64*64 + 64
#define CBOFF  36864      // cnn_b  [64]
#define PWOFF  36928      // proj_w [o][c] (64 x 128)
#define PBOFF  45120      // proj_b [64]
#define NPIX   256        // 16*16
#define IB     4          // leading guard pad (floats) of inp2

__global__ void init_kernel(const float* __restrict__ img,
                            const float* __restrict__ alpha,
                            const float* __restrict__ tau0,
                            const float* __restrict__ tau1,
                            float* __restrict__ out,
                            float* __restrict__ sm)
{
    int t = blockIdx.x * blockDim.x + threadIdx.x;

    if (blockIdx.x == 0 && threadIdx.x == 0) {
        for (int i = 0; i < 3; ++i) {
            float v0 = alpha[i*3+0], v1 = alpha[i*3+1], v2 = alpha[i*3+2];
            float mx = fmaxf(fmaxf(v0, v1), v2);
            float e0 = expf(v0-mx), e1 = expf(v1-mx), e2 = expf(v2-mx);
            float s = e0+e1+e2;
            sm[i*3+0] = e0/s; sm[i*3+1] = e1/s; sm[i*3+2] = e2/s;
            int n = i + 2;
            {
                float mv = -1e30f;
                for (int m = 0; m < n; ++m) mv = fmaxf(mv, tau0[i*4+m]);
                float e[4]; float ss = 0.f;
                for (int m = 0; m < n; ++m) { e[m] = expf(tau0[i*4+m]-mv); ss += e[m]; }
                for (int m = 0; m < 4; ++m) sm[16+i*4+m] = (m < n) ? e[m]/ss : 0.f;
            }
            {
                float mv = -1e30f;
                for (int m = 0; m < n; ++m) mv = fmaxf(mv, tau1[i*4+m]);
                float e[4]; float ss = 0.f;
                for (int m = 0; m < n; ++m) { e[m] = expf(tau1[i*4+m]-mv); ss += e[m]; }
                for (int m = 0; m < 4; ++m) sm[32+i*4+m] = (m < n) ? e[m]/ss : 0.f;
            }
        }
    }

    // zero sentinel slot (m=0) and copy img into slot m=1, float4-wide
    const int nf4 = 128*64*256/4;        // 524288
    if (t < nf4) {
        const int per_sample = 64*256/4; // 4096 float4 per map
        int b = t / per_sample;
        int r = t - b*per_sample;
        const float4* im4 = (const float4*)img;
        float4* o4 = (float4*)out;
        float4 z; z.x = z.y = z.z = z.w = 0.f;
        size_t base = (size_t)b * 5 * per_sample;
        o4[base + r]              = z;           // sentinel
        o4[base + per_sample + r] = im4[t];      // img
    }
}

template<int MOD>
__global__ __launch_bounds__(512, 2)
void module_kernel(const float* __restrict__ question,
                   const float* __restrict__ img,
                   const float* __restrict__ sm,
                   float* __restrict__ out)
{
    const int b   = blockIdx.x >> 1;
    const int oh  = blockIdx.x & 1;     // output-channel half (32 ch each)
    const int tid = threadIdx.x;

    // inp2: [64 c][18 rows][16 x], rows 0 and 17 are zero borders.
    // Guard pads front/back keep the x0-4 / x0+8 window loads in-buffer
    // (their out-of-window lanes are either never used or selected away).
    __shared__ __align__(16) float inp2[IB + 64*288 + 8];     // 73.8 KB
    // wbuf: phase A = proj weights [o][c] (8192 floats as float4);
    //       phase B = conv weights packed [och 32][c4 16][k 9][cc 4] (18432)
    __shared__ __align__(16) float wbuf[18432];               // 72 KB
    __shared__ float pb_s[64];
    __shared__ float cb_s[32];

    const float* q0 = question + (size_t)(b*3+0)*QDIM;
    const float* q1 = q0 + QDIM;
    const float* q2 = q0 + 2*QDIM;
    const float4* q04 = (const float4*)q0;
    const float4* q14 = (const float4*)q1;
    const float4* q24 = (const float4*)q2;

    const float a0 = sm[MOD*3+0], a1 = sm[MOD*3+1], a2 = sm[MOD*3+2];
    float t0[4], t1[4];
    #pragma unroll
    for (int m = 0; m < 4; ++m) { t0[m] = sm[16+MOD*4+m]; t1[m] = sm[32+MOD*4+m]; }

    // ---------- Phase A stage: proj weights (float4) + zero borders ----------
    {
        float4* proj4 = (float4*)wbuf;
        #pragma unroll
        for (int k = 0; k < 4; ++k) {
            int idx = k*512 + tid;               // 0..2047 float4s
            float4 v0 = q04[PWOFF/4 + idx];
            float4 v1 = q14[PWOFF/4 + idx];
            float4 v2 = q24[PWOFF/4 + idx];
            float4 w;
            w.x = a0*v0.x + a1*v1.x + a2*v2.x;
            w.y = a0*v0.y + a1*v1.y + a2*v2.y;
            w.z = a0*v0.z + a1*v1.z + a2*v2.z;
            w.w = a0*v0.w + a1*v1.w + a2*v2.w;
            proj4[idx] = w;
        }
        if (tid < 16) {
            float4 v0 = q04[PBOFF/4 + tid];
            float4 v1 = q14[PBOFF/4 + tid];
            float4 v2 = q24[PBOFF/4 + tid];
            float4 w;
            w.x = a0*v0.x + a1*v1.x + a2*v2.x;
            w.y = a0*v0.y + a1*v1.y + a2*v2.y;
            w.z = a0*v0.z + a1*v1.z + a2*v2.z;
            w.w = a0*v0.w + a1*v1.w + a2*v2.w;
            ((float4*)pb_s)[tid] = w;
        }
        // zero border rows: 64 ch x {row 0, row 17} x 16 floats = 512 float4
        {
            const int ch = tid >> 3, r8 = tid & 7;
            const int ry = (r8 < 4) ? 0 : 17;
            const int xq = (r8 & 3) * 4;
            float4 z; z.x = z.y = z.z = z.w = 0.f;
            *(float4*)&inp2[IB + ch*288 + ry*16 + xq] = z;
        }
    }
    __syncthreads();

    // ---------- Phase A compute: thread = (8 och, 4 px) ----------
    {
        const int oq  = tid >> 6;            // 0..7 -> 8 output channels each
        const int pgA = tid & 63;            // 4-px group
        const int px0 = pgA * 4;
        const float4* proj4 = (const float4*)wbuf;

        float acc[8][4];
        #pragma unroll
        for (int o2 = 0; o2 < 8; ++o2) {
            float pb = pb_s[oq*8 + o2];
            #pragma unroll
            for (int p = 0; p < 4; ++p) acc[o2][p] = pb;
        }

        const float* imgb = img + (size_t)b*64*NPIX;
        const float* outb = out + (size_t)b*5*64*NPIX;

        for (int c4 = 0; c4 < 16; ++c4) {
            const int c = c4*4;
            float xv0[4][4], xv1[4][4];
            #pragma unroll
            for (int j = 0; j < 4; ++j) {
                float4 v = *(const float4*)&imgb[(c+j)*NPIX + px0];
                float vv[4] = {v.x, v.y, v.z, v.w};
                float h1[4] = {0,0,0,0}, h2[4] = {0,0,0,0};
                if (MOD >= 1) {
                    float4 h = *(const float4*)&outb[(2*64 + c+j)*NPIX + px0];
                    h1[0]=h.x; h1[1]=h.y; h1[2]=h.z; h1[3]=h.w;
                }
                if (MOD >= 2) {
                    float4 h = *(const float4*)&outb[(3*64 + c+j)*NPIX + px0];
                    h2[0]=h.x; h2[1]=h.y; h2[2]=h.z; h2[3]=h.w;
                }
                #pragma unroll
                for (int p = 0; p < 4; ++p) {
                    float s0 = t0[1]*vv[p], s1 = t1[1]*vv[p];
                    if (MOD >= 1) { s0 += t0[2]*h1[p]; s1 += t1[2]*h1[p]; }
                    if (MOD >= 2) { s0 += t0[3]*h2[p]; s1 += t1[3]*h2[p]; }
                    xv0[j][p] = s0; xv1[j][p] = s1;
                }
            }
            #pragma unroll
            for (int o2 = 0; o2 < 8; ++o2) {
                const int o = oq*8 + o2;
                const float4 w0 = proj4[o*32 + c4];
                const float4 w1 = proj4[o*32 + 16 + c4];
                const float w0f[4] = {w0.x, w0.y, w0.z, w0.w};
                const float w1f[4] = {w1.x, w1.y, w1.z, w1.w};
                #pragma unroll
                for (int p = 0; p < 4; ++p) {
                    float s = acc[o2][p];
                    #pragma unroll
                    for (int j = 0; j < 4; ++j)
                        s += w0f[j]*xv0[j][p] + w1f[j]*xv1[j][p];
                    acc[o2][p] = s;
                }
            }
        }
        // write to inp2 rows 1..16
        const int ry = 1 + (px0 >> 4);
        const int xx = px0 & 15;
        #pragma unroll
        for (int o2 = 0; o2 < 8; ++o2) {
            const int o = oq*8 + o2;
            float4 w = {acc[o2][0], acc[o2][1], acc[o2][2], acc[o2][3]};
            *(float4*)&inp2[IB + o*288 + ry*16 + xx] = w;
        }
    }
    __syncthreads();   // proj reads + inp2 writes done

    // ---------- Phase B stage: packed conv weights [och][c4][k][cc] ----------
    const int obase = oh*32;
    {
        const int src4 = (obase*576) >> 2;       // float4 offset of this half
        #pragma unroll
        for (int i = 0; i < 9; ++i) {
            unsigned idx4 = i*512 + tid;         // 0..4607
            float4 v0 = q04[src4 + idx4];
            float4 v1 = q14[src4 + idx4];
            float4 v2 = q24[src4 + idx4];
            float cmb[4];
            cmb[0] = a0*v0.x + a1*v1.x + a2*v2.x;
            cmb[1] = a0*v0.y + a1*v1.y + a2*v2.y;
            cmb[2] = a0*v0.z + a1*v1.z + a2*v2.z;
            cmb[3] = a0*v0.w + a1*v1.w + a2*v2.w;
            #pragma unroll
            for (int e = 0; e < 4; ++e) {
                unsigned g  = idx4*4u + e;       // 0..18431  = och*576 + c*9 + k
                unsigned ch = g / 576u;
                unsigned r  = g - ch*576u;
                unsigned c  = r / 9u;
                unsigned k  = r - c*9u;
                wbuf[ch*576u + (c>>2)*36u + k*4u + (c&3u)] = cmb[e];
            }
        }
        if (tid < 8) {
            float4 v0 = q04[CBOFF/4 + obase/4 + tid];
            float4 v1 = q14[CBOFF/4 + obase/4 + tid];
            float4 v2 = q24[CBOFF/4 + obase/4 + tid];
            float4 w;
            w.x = a0*v0.x + a1*v1.x + a2*v2.x;
            w.y = a0*v0.y + a1*v1.y + a2*v2.y;
            w.z = a0*v0.z + a1*v1.z + a2*v2.z;
            w.w = a0*v0.w + a1*v1.w + a2*v2.w;
            ((float4*)cb_s)[tid] = w;
        }
    }
    __syncthreads();

    // ---------- Phase B compute: thread = (og of 4 och, row, quarter-row) ----------
    const int og  = tid >> 6;                // 0..7, wave-uniform
    const int pg  = tid & 63;
    const int row = pg >> 2;                 // 0..15
    const int q   = pg & 3;
    const int x0  = q << 2;

    const bool qgt0 = (q > 0);
    const bool qlt3 = (q < 3);
    const int base0 = IB + row*16 + x0 - 4;  // + c*288 + dy*16

    float acc[4][4];
    #pragma unroll
    for (int ol = 0; ol < 4; ++ol) {
        float cb = cb_s[og*4 + ol];
        #pragma unroll
        for (int p = 0; p < 4; ++p) acc[ol][p] = cb;
    }

    for (int c4i = 0; c4i < 16; ++c4i) {
        float win[4][3][6];
        #pragma unroll
        for (int cc = 0; cc < 4; ++cc) {
            const int c = c4i*4 + cc;
            #pragma unroll
            for (int dy = 0; dy < 3; ++dy) {
                const float* p = &inp2[base0 + c*288 + dy*16];
                float4 A  = *(const float4*)p;
                float4 Bv = *(const float4*)(p+4);
                float4 C  = *(const float4*)(p+8);
                win[cc][dy][0] = qgt0 ? A.w : 0.f;
                win[cc][dy][1] = Bv.x;
                win[cc][dy][2] = Bv.y;
                win[cc][dy][3] = Bv.z;
                win[cc][dy][4] = Bv.w;
                win[cc][dy][5] = qlt3 ? C.x : 0.f;
            }
        }
        #pragma unroll
        for (int ol = 0; ol < 4; ++ol) {
            const float4* wp = (const float4*)&wbuf[(og*4+ol)*576 + c4i*36];
            float4 wk4[9];
            #pragma unroll
            for (int k = 0; k < 9; ++k) wk4[k] = wp[k];     // b128 broadcasts
            const float* wk = (const float*)wk4;            // [k][cc], static idx
            #pragma unroll
            for (int cc = 0; cc < 4; ++cc) {
                #pragma unroll
                for (int p = 0; p < 4; ++p) {
                    acc[ol][p] += wk[0*4+cc]*win[cc][0][p]
                                + wk[1*4+cc]*win[cc][0][p+1]
                                + wk[2*4+cc]*win[cc][0][p+2]
                                + wk[3*4+cc]*win[cc][1][p]
                                + wk[4*4+cc]*win[cc][1][p+1]
                                + wk[5*4+cc]*win[cc][1][p+2]
                                + wk[6*4+cc]*win[cc][2][p]
                                + wk[7*4+cc]*win[cc][2][p+1]
                                + wk[8*4+cc]*win[cc][2][p+2];
                }
            }
        }
    }

    float* ob = out + ((size_t)(b*5 + 2 + MOD)*64 + obase + og*4)*NPIX + row*16 + x0;
    #pragma unroll
    for (int ol = 0; ol < 4; ++ol) {
        float4 v;
        v.x = fmaxf(acc[ol][0], 0.f);
        v.y = fmaxf(acc[ol][1], 0.f);
        v.z = fmaxf(acc[ol][2], 0.f);
        v.w = fmaxf(acc[ol][3], 0.f);
        *(float4*)&ob[ol*NPIX] = v;
    }
}

extern "C" void kernel_launch(void* const* d_in, const int* in_sizes, int n_in,
                              void* d_out, int out_size, void* d_ws, size_t ws_size,
                              hipStream_t stream)
{
    const float* question = (const float*)d_in[0];  // (128, 3, 45184)
    const float* img      = (const float*)d_in[1];  // (128, 64, 16, 16)
    const float* alpha    = (const float*)d_in[2];  // (3, 3)
    const float* tau0     = (const float*)d_in[3];  // (3, 4)
    const float* tau1     = (const float*)d_in[4];  // (3, 4)
    float* out = (float*)d_out;                     // (128, 1, 5, 64, 16, 16)
    float* sm  = (float*)d_ws;                      // 48 floats used

    init_kernel<<<2048, 256, 0, stream>>>(img, alpha, tau0, tau1, out, sm);

    module_kernel<0><<<256, 512, 0, stream>>>(question, img, sm, out);
    module_kernel<1><<<256, 512, 0, stream>>>(question, img, sm, out);
    module_kernel<2><<<256, 512, 0, stream>>>(question, img, sm, out);
}

// Round 7
// 236.654 us; speedup vs baseline: 1.4816x; 1.4816x over previous
//
#include <hip/hip_runtime.h>

#define QDIM   45184      // 64*64*9 + 64 + 2*64*64 + 64
#define CBOFF  36864
#define PWOFF  36928
#define PBOFF  45120

typedef short s8v __attribute__((ext_vector_type(8)));   // 8 x bf16 (4 VGPR)
typedef float f4v __attribute__((ext_vector_type(4)));

__device__ __forceinline__ unsigned bf_rne(float x) {
    union { float f; unsigned u; } a; a.f = x;
    return (a.u + 0x7fffu + ((a.u >> 16) & 1u)) >> 16;
}
// fp32 -> (hi, lo) bf16 pair: w ~= hi + lo with ~16 mantissa bits kept
__device__ __forceinline__ void split_bf(float w, ushort& hi, ushort& lo) {
    unsigned h = bf_rne(w);
    hi = (ushort)h;
    union { unsigned u; float f; } hf; hf.u = h << 16;
    lo = (ushort)bf_rne(w - hf.f);
}

__global__ void init_kernel(const float* __restrict__ img,
                            const float* __restrict__ alpha,
                            const float* __restrict__ tau0,
                            const float* __restrict__ tau1,
                            float* __restrict__ out,
                            float* __restrict__ sm)
{
    int t = blockIdx.x * blockDim.x + threadIdx.x;
    if (blockIdx.x == 0 && threadIdx.x == 0) {
        for (int i = 0; i < 3; ++i) {
            float v0 = alpha[i*3+0], v1 = alpha[i*3+1], v2 = alpha[i*3+2];
            float mx = fmaxf(fmaxf(v0, v1), v2);
            float e0 = expf(v0-mx), e1 = expf(v1-mx), e2 = expf(v2-mx);
            float s = e0+e1+e2;
            sm[i*3+0] = e0/s; sm[i*3+1] = e1/s; sm[i*3+2] = e2/s;
            int n = i + 2;
            for (int w = 0; w < 2; ++w) {
                const float* tsrc = w ? tau1 : tau0;
                float mv = -1e30f;
                for (int m = 0; m < n; ++m) mv = fmaxf(mv, tsrc[i*4+m]);
                float e[4]; float ss = 0.f;
                for (int m = 0; m < n; ++m) { e[m] = expf(tsrc[i*4+m]-mv); ss += e[m]; }
                for (int m = 0; m < 4; ++m) sm[16 + w*16 + i*4+m] = (m < n) ? e[m]/ss : 0.f;
            }
        }
    }
    // copy img into output slot m=1 (float4)
    const int nf4 = 128*64*256/4;        // 524288
    if (t < nf4) {
        const int per_sample = 4096;     // float4 per 64x256 map
        int b = t / per_sample;
        int r = t - b*per_sample;
        ((float4*)out)[(size_t)b*5*per_sample + per_sample + r] = ((const float4*)img)[t];
    }
}

// ---------------- projection (VALU) -> bf16 hi/lo scratch in out slot 0 ----
template<int MOD>
__global__ __launch_bounds__(512, 2)
void proj_kernel(const float* __restrict__ question,
                 const float* __restrict__ img,
                 const float* __restrict__ sm,
                 float* __restrict__ out)
{
    const int b     = blockIdx.x >> 1;
    const int chalf = blockIdx.x & 1;    // which 32 of the 64 inp channels
    const int tid   = threadIdx.x;

    __shared__ float pwt[128*32];        // proj weights transposed [c 128][ch 32]
    __shared__ float pbs[32];

    const float* q0 = question + (size_t)(b*3)*QDIM;
    const float4* q04 = (const float4*)q0;
    const float4* q14 = (const float4*)(q0 + QDIM);
    const float4* q24 = (const float4*)(q0 + 2*QDIM);

    const float a0 = sm[MOD*3+0], a1 = sm[MOD*3+1], a2 = sm[MOD*3+2];
    float t0[4], t1[4];
    #pragma unroll
    for (int m = 0; m < 4; ++m) { t0[m] = sm[16+MOD*4+m]; t1[m] = sm[32+MOD*4+m]; }

    // stage transposed combined proj weights for our 32 channels
    #pragma unroll
    for (int kk = 0; kk < 2; ++kk) {
        int idx4 = kk*512 + tid;                 // 0..1023
        int o = idx4 >> 5, i32 = idx4 & 31;      // ch row, float4-in-row
        float4 v0 = q04[PWOFF/4 + (chalf*32 + o)*32 + i32];
        float4 v1 = q14[PWOFF/4 + (chalf*32 + o)*32 + i32];
        float4 v2 = q24[PWOFF/4 + (chalf*32 + o)*32 + i32];
        float cmb[4] = { a0*v0.x + a1*v1.x + a2*v2.x,
                         a0*v0.y + a1*v1.y + a2*v2.y,
                         a0*v0.z + a1*v1.z + a2*v2.z,
                         a0*v0.w + a1*v1.w + a2*v2.w };
        #pragma unroll
        for (int e = 0; e < 4; ++e) pwt[(i32*4 + e)*32 + o] = cmb[e];
    }
    if (tid < 8) {
        float4 v0 = q04[PBOFF/4 + chalf*8 + tid];
        float4 v1 = q14[PBOFF/4 + chalf*8 + tid];
        float4 v2 = q24[PBOFF/4 + chalf*8 + tid];
        pbs[tid*4+0] = a0*v0.x + a1*v1.x + a2*v2.x;
        pbs[tid*4+1] = a0*v0.y + a1*v1.y + a2*v2.y;
        pbs[tid*4+2] = a0*v0.z + a1*v1.z + a2*v2.z;
        pbs[tid*4+3] = a0*v0.w + a1*v1.w + a2*v2.w;
    }
    __syncthreads();

    const int og = tid >> 6;             // wave-uniform: 4 channels each
    const int p4 = tid & 63;             // pixel quad
    const float4* im4 = (const float4*)(img + (size_t)b*16384);
    const float4* h14 = (const float4*)(out + ((size_t)b*5 + 2)*16384);
    const float4* h24 = (const float4*)(out + ((size_t)b*5 + 3)*16384);

    float acc[4][4];
    #pragma unroll
    for (int j = 0; j < 4; ++j) {
        float pb = pbs[og*4 + j];
        #pragma unroll
        for (int p = 0; p < 4; ++p) acc[j][p] = pb;
    }

    for (int cc = 0; cc < 64; ++cc) {
        float4 vi = im4[cc*64 + p4];
        float vv[4] = {vi.x, vi.y, vi.z, vi.w};
        float lhs[4], rhs[4];
        float h1v[4] = {0,0,0,0}, h2v[4] = {0,0,0,0};
        if (MOD >= 1) { float4 h = h14[cc*64 + p4]; h1v[0]=h.x; h1v[1]=h.y; h1v[2]=h.z; h1v[3]=h.w; }
        if (MOD >= 2) { float4 h = h24[cc*64 + p4]; h2v[0]=h.x; h2v[1]=h.y; h2v[2]=h.z; h2v[3]=h.w; }
        #pragma unroll
        for (int p = 0; p < 4; ++p) {
            float s0 = t0[1]*vv[p], s1 = t1[1]*vv[p];
            if (MOD >= 1) { s0 += t0[2]*h1v[p]; s1 += t1[2]*h1v[p]; }
            if (MOD >= 2) { s0 += t0[3]*h2v[p]; s1 += t1[3]*h2v[p]; }
            lhs[p] = s0; rhs[p] = s1;
        }
        float4 wl = *(const float4*)&pwt[cc*32 + og*4];        // broadcast
        float4 wr = *(const float4*)&pwt[(64+cc)*32 + og*4];
        const float wlf[4] = {wl.x, wl.y, wl.z, wl.w};
        const float wrf[4] = {wr.x, wr.y, wr.z, wr.w};
        #pragma unroll
        for (int j = 0; j < 4; ++j)
            #pragma unroll
            for (int p = 0; p < 4; ++p)
                acc[j][p] += wlf[j]*lhs[p] + wrf[j]*rhs[p];
    }

    // write bf16 hi/lo planes: scratch = out slot 0, [16r][16x][64c], hi then lo
    ushort* scr = (ushort*)(out + (size_t)b*81920);
    const int ch0 = chalf*32 + og*4;
    #pragma unroll
    for (int p = 0; p < 4; ++p) {
        int e = (p4*4 + p)*64 + ch0;
        ushort hv[4], lv[4];
        #pragma unroll
        for (int j = 0; j < 4; ++j) split_bf(acc[j][p], hv[j], lv[j]);
        *(ushort4*)&scr[e]         = make_ushort4(hv[0], hv[1], hv[2], hv[3]);
        *(ushort4*)&scr[16384 + e] = make_ushort4(lv[0], lv[1], lv[2], lv[3]);
    }
}

// ---------------- conv (MFMA, 9 shift-GEMMs, bf16 hi/lo) --------------------
template<int MOD>
__global__ __launch_bounds__(512, 2)
void conv_kernel(const float* __restrict__ question,
                 const float* __restrict__ sm,
                 float* __restrict__ out)
{
    const int b     = blockIdx.x >> 1;
    const int ohalf = blockIdx.x & 1;
    const int tid   = threadIdx.x;

    // inp: [2 planes][18 row][18 x][64 c] bf16, c rotated by 8*(x&7)
    __shared__ ushort inp_s[2*20736];    // 82944 B
    // weights: [2 planes][9 sh][32 oc][64 c] bf16, c rotated by 8*(oc&7)
    __shared__ ushort w_s[2*18432];      // 73728 B
    __shared__ float  cb_s[32];

    const float* q0 = question + (size_t)(b*3)*QDIM;
    const float4* q04 = (const float4*)q0;
    const float4* q14 = (const float4*)(q0 + QDIM);
    const float4* q24 = (const float4*)(q0 + 2*QDIM);
    const float a0 = sm[MOD*3+0], a1 = sm[MOD*3+1], a2 = sm[MOD*3+2];

    // ---- stage conv weights (combine + hi/lo split + rotated scatter) ----
    const int src4 = ohalf*4608;
    #pragma unroll
    for (int i = 0; i < 9; ++i) {
        unsigned idx4 = i*512u + tid;                    // 0..4607
        float4 v0 = q04[src4 + idx4];
        float4 v1 = q14[src4 + idx4];
        float4 v2 = q24[src4 + idx4];
        float cmb[4] = { a0*v0.x + a1*v1.x + a2*v2.x,
                         a0*v0.y + a1*v1.y + a2*v2.y,
                         a0*v0.z + a1*v1.z + a2*v2.z,
                         a0*v0.w + a1*v1.w + a2*v2.w };
        #pragma unroll
        for (int e = 0; e < 4; ++e) {
            unsigned g  = idx4*4u + e;                   // oc*576 + c*9 + sh
            unsigned oc = g / 576u;
            unsigned r  = g - oc*576u;
            unsigned c  = r / 9u;
            unsigned sh = r - c*9u;
            unsigned d  = sh*2048u + oc*64u + ((c + 8u*(oc & 7u)) & 63u);
            ushort hi, lo; split_bf(cmb[e], hi, lo);
            w_s[d] = hi; w_s[18432u + d] = lo;
        }
    }
    // ---- stage inp from scratch (bulk b128 copy with rotation) ----
    const uint4* scr4 = (const uint4*)(out + (size_t)b*81920);
    #pragma unroll
    for (int it = 0; it < 8; ++it) {
        int id = it*512 + tid;                           // 0..4095
        int plane = id >> 11, g = id & 2047;
        int k = g & 7, px = (g >> 3) & 15, py = g >> 7;
        uint4 v = scr4[id];
        int d = plane*20736 + (py+1)*1152 + (px+1)*64 + (((k + ((px+1) & 7)) & 7) << 3);
        *(uint4*)&inp_s[d] = v;
    }
    // ---- zero borders ----
    for (int id = tid; id < 1088; id += 512) {
        int pos = id >> 4, rest = id & 15;
        int plane = rest >> 3, k = rest & 7;
        int row, x;
        if (pos < 18)      { row = 0;        x = pos;      }
        else if (pos < 36) { row = 17;       x = pos - 18; }
        else if (pos < 52) { row = pos - 35; x = 0;        }
        else               { row = pos - 51; x = 17;       }
        uint4 z = {0,0,0,0};
        *(uint4*)&inp_s[plane*20736 + row*1152 + x*64 + (k << 3)] = z;
    }
    if (tid < 8) {
        float4 v0 = q04[CBOFF/4 + ohalf*8 + tid];
        float4 v1 = q14[CBOFF/4 + ohalf*8 + tid];
        float4 v2 = q24[CBOFF/4 + ohalf*8 + tid];
        cb_s[tid*4+0] = a0*v0.x + a1*v1.x + a2*v2.x;
        cb_s[tid*4+1] = a0*v0.y + a1*v1.y + a2*v2.y;
        cb_s[tid*4+2] = a0*v0.z + a1*v1.z + a2*v2.z;
        cb_s[tid*4+3] = a0*v0.w + a1*v1.w + a2*v2.w;
    }
    __syncthreads();

    // ---- MFMA main: wave w handles N-tiles (py) {2w, 2w+1}, both M-tiles ----
    const int w8  = tid >> 6;
    const int l   = tid & 63;
    const int l15 = l & 15, lk = l >> 4;
    const int nt0 = w8 * 2;

    f4v acc[2][2];
    #pragma unroll
    for (int mt = 0; mt < 2; ++mt)
        #pragma unroll
        for (int nt = 0; nt < 2; ++nt)
            acc[mt][nt] = (f4v){0.f, 0.f, 0.f, 0.f};

    #pragma unroll
    for (int dy = 0; dy < 3; ++dy) {
        #pragma unroll
        for (int dx = 0; dx < 3; ++dx) {
            const int sh = dy*3 + dx;
            const int x  = l15 + dx;             // stored x index 0..17
            const int rx = 8*(x & 7);
            #pragma unroll
            for (int ks = 0; ks < 2; ++ks) {
                const int c0 = ks*32 + lk*8;
                s8v a[2][2], bb[2][2];
                #pragma unroll
                for (int mt = 0; mt < 2; ++mt) {
                    const int oc = mt*16 + l15;
                    const int ae = sh*2048 + oc*64 + ((c0 + 8*(oc & 7)) & 63);
                    a[mt][0] = *(const s8v*)&w_s[ae];
                    a[mt][1] = *(const s8v*)&w_s[18432 + ae];
                }
                #pragma unroll
                for (int nt = 0; nt < 2; ++nt) {
                    const int be = ((nt0 + nt + dy)*18 + x)*64 + ((c0 + rx) & 63);
                    bb[nt][0] = *(const s8v*)&inp_s[be];
                    bb[nt][1] = *(const s8v*)&inp_s[20736 + be];
                }
                #pragma unroll
                for (int mt = 0; mt < 2; ++mt)
                    #pragma unroll
                    for (int nt = 0; nt < 2; ++nt) {
                        acc[mt][nt] = __builtin_amdgcn_mfma_f32_16x16x32_bf16(a[mt][0], bb[nt][0], acc[mt][nt], 0, 0, 0);
                        acc[mt][nt] = __builtin_amdgcn_mfma_f32_16x16x32_bf16(a[mt][0], bb[nt][1], acc[mt][nt], 0, 0, 0);
                        acc[mt][nt] = __builtin_amdgcn_mfma_f32_16x16x32_bf16(a[mt][1], bb[nt][0], acc[mt][nt], 0, 0, 0);
                    }
            }
        }
    }

    // ---- epilogue: +bias, ReLU, store (C/D: col=lane&15, row=(lane>>4)*4+r) ----
    float* ob = out + ((size_t)(b*5 + 2 + MOD)*64 + ohalf*32)*256;
    #pragma unroll
    for (int mt = 0; mt < 2; ++mt) {
        #pragma unroll
        for (int nt = 0; nt < 2; ++nt) {
            const int py = nt0 + nt;
            #pragma unroll
            for (int r = 0; r < 4; ++r) {
                const int ocl = mt*16 + lk*4 + r;
                float v = acc[mt][nt][r] + cb_s[ocl];
                ob[ocl*256 + py*16 + l15] = fmaxf(v, 0.f);
            }
        }
    }
}

__global__ void zero_sent(float* __restrict__ out)
{
    int t = blockIdx.x*blockDim.x + threadIdx.x;
    if (t < 524288) {
        int b = t >> 12, r = t & 4095;
        float4 z = {0,0,0,0};
        ((float4*)out)[(size_t)b*20480 + r] = z;
    }
}

extern "C" void kernel_launch(void* const* d_in, const int* in_sizes, int n_in,
                              void* d_out, int out_size, void* d_ws, size_t ws_size,
                              hipStream_t stream)
{
    const float* question = (const float*)d_in[0];
    const float* img      = (const float*)d_in[1];
    const float* alpha    = (const float*)d_in[2];
    const float* tau0     = (const float*)d_in[3];
    const float* tau1     = (const float*)d_in[4];
    float* out = (float*)d_out;          // (128, 1, 5, 64, 16, 16)
    float* sm  = (float*)d_ws;           // 48 floats

    init_kernel<<<2048, 256, 0, stream>>>(img, alpha, tau0, tau1, out, sm);

    proj_kernel<0><<<256, 512, 0, stream>>>(question, img, sm, out);
    conv_kernel<0><<<256, 512, 0, stream>>>(question, sm, out);
    proj_kernel<1><<<256, 512, 0, stream>>>(question, img, sm, out);
    conv_kernel<1><<<256, 512, 0, stream>>>(question, sm, out);
    proj_kernel<2><<<256, 512, 0, stream>>>(question, img, sm, out);
    conv_kernel<2><<<256, 512, 0, stream>>>(question, sm, out);

    zero_sent<<<1024, 512, 0, stream>>>(out);
}